// Round 9
// baseline (358.078 us; speedup 1.0000x reference)
//
#include <hip/hip_runtime.h>
#include <hip/hip_bf16.h>

#define NROWS 16384      // 16*32*32
#define EDIM  256
#define NE    8192
#define OUT_N 4194304    // 16*256*32*32

typedef _Float16 v8h __attribute__((ext_vector_type(8)));
typedef _Float16 v4h __attribute__((ext_vector_type(4)));
typedef float    v4f __attribute__((ext_vector_type(4)));

// ---- main-path ws layout (float units) ---- (16.2 MB < 17.1 MB proven)
#define OFF_S     0                        // 16384
#define OFF_E     16384                    // 8192
#define OFF_MARG  24576                    // 16384
#define OFF_IDX   40960                    // 16384 i32
#define OFF_CH    57600                    // 16384*128 fp16 = 1048576 float slots
#define OFF_ZFH   1106176                  // 16384*256 fp16 = 2097152 float slots
#define OFF_EFH   3203328                  // 8192*256 fp16 = 1048576 float slots
#define OFF_LOSSP 4251904                  // 512 block partials
#define WS_NEED_FLOATS 4252416

#define ESCALE   1048576.0f                // 2^20 (exact); descale 2^-19 on d
#define DESCALE  0x1p-19f

static __device__ __forceinline__ unsigned short to_fp16_bits(float v) {
    _Float16 h = (_Float16)v;
    return __builtin_bit_cast(unsigned short, h);
}

// =======================================================================
// k_pre (validated R6-R8, unchanged): z rows (S, MARG, z cvt fp16),
// emb (cvt*2^20 + E sums).
// =======================================================================
__global__ __launch_bounds__(256) void k_pre(const float* __restrict__ z,
                                             const float* __restrict__ emb,
                                             float* __restrict__ ws) {
    float* S = ws + OFF_S;
    float* E = ws + OFF_E;
    float* MARG = ws + OFF_MARG;
    unsigned short* zfh = (unsigned short*)(ws + OFF_ZFH);
    unsigned short* efh = (unsigned short*)(ws + OFF_EFH);

    const int blk = blockIdx.x, tid = threadIdx.x;

    __shared__ float T[64][260];
    __shared__ double SD[64][4];
    __shared__ double AD[64][4];

    if (blk < 256) {
        const int r0 = blk * 64;
        const int b = r0 >> 10, hw0 = r0 & 1023;   // 64-row tile never crosses b
        const int rr = tid & 63, kq = tid >> 6;
        const float* zp = z + (size_t)b * 262144 + hw0 + rr;
        double s = 0.0, a = 0.0;
#pragma unroll 8
        for (int kk = 0; kk < 64; ++kk) {
            int k = kq * 64 + kk;
            float v = zp[(size_t)k << 10];
            s += (double)v * (double)v;
            a += fabs((double)v);
            T[rr][k] = v;
        }
        SD[rr][kq] = s; AD[rr][kq] = a;
        __syncthreads();
        if (tid < 64) {
            double ss = SD[tid][0] + SD[tid][1] + SD[tid][2] + SD[tid][3];
            double aa = AD[tid][0] + AD[tid][1] + AD[tid][2] + AD[tid][3];
            S[r0 + tid] = (float)ss;
            MARG[r0 + tid] = 1.2e-4f + 6.5e-7f * (float)aa;
        }
        const int m = tid >> 2, koff = (tid & 3) * 64;
#pragma unroll
        for (int c = 0; c < 8; ++c) {
            unsigned short us[8];
#pragma unroll
            for (int j = 0; j < 8; ++j) us[j] = to_fp16_bits(T[m][koff + c * 8 + j]);
            *(uint4*)(zfh + (size_t)(r0 + m) * 256 + koff + c * 8) = *(uint4*)us;
        }
    } else {
        const int eb = blk - 256;
        const float* src = emb + (size_t)eb * 16384;
        unsigned short* dst = efh + (size_t)eb * 16384;
#pragma unroll
        for (int it = 0; it < 16; ++it) {
            int e4 = tid + it * 256;
            float4 v = ((const float4*)src)[e4];
            unsigned short us[4] = {to_fp16_bits(v.x * ESCALE), to_fp16_bits(v.y * ESCALE),
                                    to_fp16_bits(v.z * ESCALE), to_fp16_bits(v.w * ESCALE)};
            *(uint2*)(dst + (size_t)e4 * 4) = *(uint2*)us;
        }
        const int n0 = eb * 64;
        const int rr = tid & 63, kq = tid >> 6;
        const float* p = emb + (size_t)(n0 + rr) * 256 + kq * 64;
        double s = 0.0;
#pragma unroll 8
        for (int kk = 0; kk < 64; ++kk) { float v = p[kk]; s += (double)v * (double)v; }
        SD[rr][kq] = s;
        __syncthreads();
        if (tid < 64)
            E[n0 + tid] = (float)(SD[tid][0] + SD[tid][1] + SD[tid][2] + SD[tid][3]);
    }
}

// =======================================================================
// k_gemm (validated R6-R8, unchanged): fp16 MFMA 128x128, K=256; per-(row,
// 64-col chunk) min of d_approx stored fp16 rel to S[r]. Deterministic.
// =======================================================================
__global__ __launch_bounds__(256) void k_gemm(
    const unsigned short* __restrict__ zfh, const unsigned short* __restrict__ efh,
    const float* __restrict__ S, const float* __restrict__ E,
    _Float16* __restrict__ CH) {
    __shared__ __align__(16) unsigned short As[128 * 64];
    __shared__ __align__(16) unsigned short Bs[128 * 64];

    const int tid = threadIdx.x;
    const int lane = tid & 63, wave = tid >> 6;
    const int wm = (wave & 1) * 64, wn = (wave >> 1) * 64;
    const int row0 = blockIdx.x * 128, col0 = blockIdx.y * 128;
    const int lm = lane & 15, lq = lane >> 4;

    v4f acc[4][4];
#pragma unroll
    for (int i = 0; i < 4; ++i)
#pragma unroll
        for (int j = 0; j < 4; ++j) acc[i][j] = (v4f){0.f, 0.f, 0.f, 0.f};

    for (int kt = 0; kt < 4; ++kt) {
        const int kbase = kt * 64;
#pragma unroll
        for (int it = 0; it < 4; ++it) {
            int e = tid + it * 256;
            int m = e >> 3, c = e & 7;
            uint4 va = *(const uint4*)(zfh + (size_t)(row0 + m) * 256 + kbase + c * 8);
            *(uint4*)(As + m * 64 + ((c ^ (m & 7)) << 3)) = va;
            uint4 vb = *(const uint4*)(efh + (size_t)(col0 + m) * 256 + kbase + c * 8);
            *(uint4*)(Bs + m * 64 + ((c ^ (m & 7)) << 3)) = vb;
        }
        __syncthreads();
#pragma unroll
        for (int s = 0; s < 2; ++s) {
            v8h af[4], bfr[4];
#pragma unroll
            for (int fi = 0; fi < 4; ++fi) {
                int m = wm + fi * 16 + lm;
                int c = (s << 2) | lq;
                af[fi] = *(const v8h*)(As + m * 64 + ((c ^ (m & 7)) << 3));
            }
#pragma unroll
            for (int fj = 0; fj < 4; ++fj) {
                int n = wn + fj * 16 + lm;
                int c = (s << 2) | lq;
                bfr[fj] = *(const v8h*)(Bs + n * 64 + ((c ^ (n & 7)) << 3));
            }
#pragma unroll
            for (int fi = 0; fi < 4; ++fi)
#pragma unroll
                for (int fj = 0; fj < 4; ++fj)
                    acc[fi][fj] = __builtin_amdgcn_mfma_f32_16x16x32_f16(
                        af[fi], bfr[fj], acc[fi][fj], 0, 0, 0);
        }
        __syncthreads();
    }

    float Sl[16];
#pragma unroll
    for (int fi = 0; fi < 4; ++fi)
#pragma unroll
        for (int r = 0; r < 4; ++r)
            Sl[fi * 4 + r] = S[row0 + wm + fi * 16 + lq * 4 + r];
    float En[4];
#pragma unroll
    for (int fj = 0; fj < 4; ++fj) En[fj] = E[col0 + wn + fj * 16 + lm];

    float dmin[16];
#pragma unroll
    for (int fi = 0; fi < 4; ++fi)
#pragma unroll
        for (int r = 0; r < 4; ++r) {
            float dm = __builtin_inff();
#pragma unroll
            for (int fj = 0; fj < 4; ++fj) {
                float d = (Sl[fi * 4 + r] + En[fj]) - acc[fi][fj][r] * DESCALE;
                dm = fminf(dm, d);
            }
            dmin[fi * 4 + r] = dm;
        }
#pragma unroll
    for (int msk = 1; msk < 16; msk <<= 1)
#pragma unroll
        for (int i = 0; i < 16; ++i)
            dmin[i] = fminf(dmin[i], __shfl_xor(dmin[i], msk, 64));

    if (lm == 0) {
        const int cb = blockIdx.y * 2 + (wn >> 6);
#pragma unroll
        for (int i = 0; i < 16; ++i) {
            int fi = i >> 2, r = i & 3;
            int gm = row0 + wm + fi * 16 + lq * 4 + r;
            float rel = dmin[i] - Sl[i];             // Sterbenz: exact
            CH[(size_t)gm * 128 + cb] = (_Float16)rel;
        }
    }
}

// =======================================================================
// k_rescore v4: 1 row per wave, 4 waves/block (4096 blocks — fine-grained).
// No fp32 z staging: refine uses ZFH (fp16 z, coalesced 512B/row; margin
// headroom >=1.35x worst-case) x EFH. Exact fp32 chain (bit-identical
// ascending-k fmaf) gets z via lazy scattered register gather (once per
// row, L3-resident) + uniform-index __shfl broadcast. Deterministic:
// no atomics, fixed order, wave-uniform branches.
// =======================================================================
__global__ __launch_bounds__(256) void k_rescore(
    const float* __restrict__ z, const float* __restrict__ emb,
    const float* __restrict__ S, const float* __restrict__ E,
    const float* __restrict__ MARG,
    const unsigned short* __restrict__ zfh,
    const unsigned short* __restrict__ efh,
    const _Float16* __restrict__ CH,
    int* __restrict__ IDX, float* __restrict__ idx_f) {
    __shared__ _Float16 zh[4][264];
    const int tid = threadIdx.x;
    const int lane = tid & 63, wave = tid >> 6;
    const int r = blockIdx.x * 4 + wave;
    const int b = r >> 10, hw = r & 1023;

    // stage the row's fp16 z (512B contiguous per wave, 2-way LDS write: free)
    *(uint2*)&zh[wave][lane * 4] = *(const uint2*)(zfh + (size_t)r * 256 + lane * 4);

    float m0 = (float)CH[(size_t)r * 128 + lane];
    float m1 = (float)CH[(size_t)r * 128 + 64 + lane];
    float g = fminf(m0, m1);
#pragma unroll
    for (int off = 32; off; off >>= 1) g = fminf(g, __shfl_xor(g, off, 64));
    const float thr = g + MARG[r];
    const float MB  = 0.75f * MARG[r];
    const float Sr = S[r];

    unsigned long long p0 = __ballot(m0 <= thr);
    unsigned long long p1 = __ballot(m1 <= thr);

    float zreg[4];           // fp32 z, k = lane + 64*t, gathered lazily
    bool zld = false;

    unsigned long long key = ~0ull;
    float grun = __builtin_inff();
    const v8h* zhp = (const v8h*)&zh[wave][0];
    for (int half = 0; half < 2; ++half) {
        unsigned long long pm = half ? p1 : p0;
        while (pm) {                         // wave-uniform loop
            int c = __ffsll((long long)pm) - 1; pm &= pm - 1;
            const int cb = half * 64 + c;
            const int j = (cb << 6) | lane;
            // ---- refine: fp16 z (LDS broadcast) x fp16 emb (scaled 2^20)
            const v8h* ehp = (const v8h*)(efh + ((size_t)j << 8));
            float macc = 0.0f;
#pragma unroll 8
            for (int k8 = 0; k8 < 32; ++k8) {
                v8h ev = ehp[k8];
                v8h zv = zhp[k8];
#pragma unroll
                for (int i = 0; i < 8; ++i)
                    macc = fmaf((float)zv[i], (float)ev[i], macc);  // v_fma_mix
            }
            float dref = (Sr + E[j]) - macc * DESCALE;
            float lmin = dref;
#pragma unroll
            for (int off = 32; off; off >>= 1) lmin = fminf(lmin, __shfl_xor(lmin, off, 64));
            grun = fminf(grun, lmin);
            // superset-safe: stale-high grun only adds survivors
            unsigned long long sm = __ballot(dref <= grun + MB);
            while (sm) {                     // ~1.2 survivors/row typical
                int s = __ffsll((long long)sm) - 1; sm &= sm - 1;
                const int js = (cb << 6) | s;
                if (!zld) {                  // wave-uniform lazy gather (once/row)
#pragma unroll
                    for (int t = 0; t < 4; ++t)
                        zreg[t] = z[(size_t)b * 262144 +
                                    (size_t)(lane + 64 * t) * 1024 + hw];
                    zld = true;
                }
                // ---- exact fp32 chain, bit-identical to validated path:
                // ascending k, z_k via uniform-index shuffle broadcast
                const float4* ep4 = (const float4*)(emb + ((size_t)js << 8));
                float m = 0.0f;
#pragma unroll 8
                for (int k4 = 0; k4 < 64; ++k4) {
                    float4 e4 = ep4[k4];
                    int t = k4 >> 4;
#pragma unroll
                    for (int i = 0; i < 4; ++i) {
                        float zk = __shfl(zreg[t], (k4 * 4 + i) & 63, 64);
                        float ek = (i == 0) ? e4.x : (i == 1) ? e4.y : (i == 2) ? e4.z : e4.w;
                        m = fmaf(zk, ek, m);
                    }
                }
                float d = (Sr + E[js]) - 2.0f * m;   // d > 0 -> bits monotone
                unsigned long long kk =
                    ((unsigned long long)__float_as_uint(d) << 32) | (unsigned)js;
                key = kk < key ? kk : key;           // lane-uniform
            }
        }
    }
    if (lane == 0) {
        int j = (int)(key & 0xFFFFFFFFull);
        IDX[r] = j;
        idx_f[r] = (float)j;
    }
}

// =======================================================================
// k_out v2 (validated R8, unchanged) + k_fin (deterministic loss)
// =======================================================================
__global__ __launch_bounds__(256) void k_out(const float* __restrict__ z,
                                             const float* __restrict__ emb,
                                             const int* __restrict__ idx,
                                             float* __restrict__ out,
                                             float* __restrict__ lossp) {
    __shared__ __align__(16) float EB[32 * 260];
    __shared__ float red[256];
    __shared__ int ids[32];
    const int tid = threadIdx.x;
    const int r0 = blockIdx.x * 32;            // 32 consecutive rows, same b
    const int b = r0 >> 10, hw0 = r0 & 1023;

    if (tid < 32) ids[tid] = idx[r0 + tid];
    __syncthreads();
#pragma unroll
    for (int it = 0; it < 8; ++it) {
        int i = tid + it * 256;                // 0..2047
        int rr = i >> 6, k4 = i & 63;
        float4 v = *(const float4*)(emb + (size_t)ids[rr] * 256 + k4 * 4);
        *(float4*)(EB + rr * 260 + k4 * 4) = v;
    }
    __syncthreads();

    const float* zb = z + ((size_t)b << 18) + hw0;
    float*       ob = out + ((size_t)b << 18) + hw0;
    const int hq = tid & 7;
    const int cg = tid >> 3;
    float lsum = 0.0f;
#pragma unroll
    for (int it = 0; it < 8; ++it) {
        int c = it * 32 + cg;
        float4 zv = *(const float4*)(zb + (size_t)c * 1024 + hq * 4);
        float e0 = EB[(hq * 4 + 0) * 260 + c];
        float e1 = EB[(hq * 4 + 1) * 260 + c];
        float e2 = EB[(hq * 4 + 2) * 260 + c];
        float e3 = EB[(hq * 4 + 3) * 260 + c];
        float d0 = e0 - zv.x, d1 = e1 - zv.y, d2 = e2 - zv.z, d3 = e3 - zv.w;
        float4 ov = {zv.x + d0, zv.y + d1, zv.z + d2, zv.w + d3};
        *(float4*)(ob + (size_t)c * 1024 + hq * 4) = ov;
        lsum += d0 * d0 + d1 * d1 + d2 * d2 + d3 * d3;
    }
    red[tid] = lsum;
    __syncthreads();
    for (int off = 128; off; off >>= 1) {
        if (tid < off) red[tid] += red[tid + off];
        __syncthreads();
    }
    if (tid == 0) lossp[blockIdx.x] = red[0];
}

__global__ __launch_bounds__(256) void k_fin(const float* __restrict__ lossp,
                                             float* __restrict__ out_loss) {
    __shared__ float red[256];
    const int tid = threadIdx.x;
    red[tid] = lossp[tid] + lossp[tid + 256];
    __syncthreads();
    for (int off = 128; off; off >>= 1) {
        if (tid < off) red[tid] += red[tid + off];
        __syncthreads();
    }
    if (tid == 0) {
        float m = red[0] / 4194304.0f;
        out_loss[0] = m + 0.25f * m;
    }
}

// =======================================================================
// Fallback path (round-2 core, proven): used only if ws is too small.
// =======================================================================
#define FWS_S     0
#define FWS_E     (FWS_S + NROWS)
#define FWS_KEY   (FWS_E + NE)
#define FWS_IDX   (FWS_KEY + NROWS * 2)
#define FWS_LOSSP (FWS_IDX + NROWS)

__global__ void f_rowsum_z(const float* __restrict__ z, float* __restrict__ S) {
    int r = blockIdx.x * 256 + threadIdx.x;
    int b = r >> 10, hw = r & 1023;
    const float* p = z + (size_t)b * 262144 + hw;
    double s = 0.0;
#pragma unroll 8
    for (int c = 0; c < 256; ++c) { float v = p[(size_t)c * 1024]; s += (double)v * (double)v; }
    S[r] = (float)s;
}
__global__ void f_rowsum_e(const float* __restrict__ emb, float* __restrict__ E) {
    int row = blockIdx.x * 4 + (threadIdx.x >> 6);
    int lane = threadIdx.x & 63;
    const float* p = emb + (size_t)row * 256;
    double s = 0.0;
#pragma unroll
    for (int i = 0; i < 4; ++i) { float v = p[lane + i * 64]; s += (double)v * (double)v; }
    for (int off = 32; off; off >>= 1) s += __shfl_down(s, off, 64);
    if (lane == 0) E[row] = (float)s;
}
__global__ __launch_bounds__(256, 4) void f_gemm_argmin(
    const float* __restrict__ z, const float* __restrict__ emb,
    const float* __restrict__ S, const float* __restrict__ E,
    unsigned long long* __restrict__ keys) {
    __shared__ __align__(16) float As[32][128];
    __shared__ __align__(16) float Bs[32][133];
    const int tid = threadIdx.x;
    const int tx = tid & 15, ty = tid >> 4;
    const int row0 = blockIdx.x * 128, col0 = blockIdx.y * 128;
    const int b = row0 >> 10, hw0 = row0 & 1023;
    const float* zb = z + (size_t)b * 262144 + hw0;
    float acc[8][8];
#pragma unroll
    for (int i = 0; i < 8; ++i)
#pragma unroll
        for (int j = 0; j < 8; ++j) acc[i][j] = 0.0f;
    for (int kt = 0; kt < 8; ++kt) {
        const int kbase = kt * 32;
#pragma unroll
        for (int it = 0; it < 4; ++it) {
            int e = tid + it * 256;
            int k = e >> 5, m4 = (e & 31) << 2;
            *(float4*)&As[k][m4] = *(const float4*)(zb + (size_t)(kbase + k) * 1024 + m4);
        }
#pragma unroll
        for (int it = 0; it < 4; ++it) {
            int e = tid + it * 256;
            int n = e >> 3, k4 = (e & 7) << 2;
            float4 v = *(const float4*)(emb + (size_t)(col0 + n) * 256 + kbase + k4);
            Bs[k4 + 0][n] = v.x; Bs[k4 + 1][n] = v.y;
            Bs[k4 + 2][n] = v.z; Bs[k4 + 3][n] = v.w;
        }
        __syncthreads();
#pragma unroll 8
        for (int k = 0; k < 32; ++k) {
            float4 a0 = *(const float4*)&As[k][tx * 4];
            float4 a1 = *(const float4*)&As[k][64 + tx * 4];
            float4 b0 = *(const float4*)&Bs[k][ty * 4];
            float4 b1 = *(const float4*)&Bs[k][64 + ty * 4];
            float a_[8] = {a0.x, a0.y, a0.z, a0.w, a1.x, a1.y, a1.z, a1.w};
            float b_[8] = {b0.x, b0.y, b0.z, b0.w, b1.x, b1.y, b1.z, b1.w};
#pragma unroll
            for (int i = 0; i < 8; ++i)
#pragma unroll
                for (int j = 0; j < 8; ++j) acc[i][j] += a_[i] * b_[j];
        }
        __syncthreads();
    }
    float4 S0 = *(const float4*)(S + row0 + tx * 4);
    float4 S1 = *(const float4*)(S + row0 + 64 + tx * 4);
    float4 E0 = *(const float4*)(E + col0 + ty * 4);
    float4 E1 = *(const float4*)(E + col0 + 64 + ty * 4);
    float Sr[8] = {S0.x, S0.y, S0.z, S0.w, S1.x, S1.y, S1.z, S1.w};
    float Ec[8] = {E0.x, E0.y, E0.z, E0.w, E1.x, E1.y, E1.z, E1.w};
    unsigned long long best[8];
#pragma unroll
    for (int i = 0; i < 8; ++i) best[i] = ~0ull;
#pragma unroll
    for (int j = 0; j < 8; ++j) {
        int col = col0 + ((j < 4) ? (ty * 4 + j) : (64 + ty * 4 + j - 4));
#pragma unroll
        for (int i = 0; i < 8; ++i) {
            float t = Sr[i] + Ec[j];
            float d = t - 2.0f * acc[i][j];
            unsigned ud = __float_as_uint(d);
            ud = (ud & 0x80000000u) ? ~ud : (ud | 0x80000000u);
            unsigned long long key = ((unsigned long long)ud << 32) | (unsigned)col;
            if (key < best[i]) best[i] = key;
        }
    }
    __syncthreads();
    unsigned long long* Sk = (unsigned long long*)&As[0][0];
#pragma unroll
    for (int i = 0; i < 4; ++i) {
        Sk[ty * 128 + tx * 4 + i] = best[i];
        Sk[ty * 128 + 64 + tx * 4 + i] = best[4 + i];
    }
    __syncthreads();
    if (tid < 128) {
        unsigned long long m = ~0ull;
#pragma unroll
        for (int t = 0; t < 16; ++t) {
            unsigned long long v = Sk[t * 128 + tid];
            m = v < m ? v : m;
        }
        atomicMin(&keys[row0 + tid], m);
    }
}
__global__ void f_merge(const unsigned long long* __restrict__ keys,
                        int* __restrict__ idx, float* __restrict__ idx_f) {
    int r = blockIdx.x * 256 + threadIdx.x;
    int bestj = (int)(keys[r] & 0xFFFFFFFFull);
    idx[r] = bestj;
    idx_f[r] = (float)bestj;
}

extern "C" void kernel_launch(void* const* d_in, const int* in_sizes, int n_in,
                              void* d_out, int out_size, void* d_ws, size_t ws_size,
                              hipStream_t stream) {
    const float* z   = (const float*)d_in[0];
    const float* emb = (const float*)d_in[1];
    float* out = (float*)d_out;
    float* ws  = (float*)d_ws;

    if (ws_size >= (size_t)WS_NEED_FLOATS * 4) {
        float* S = ws + OFF_S;
        float* E = ws + OFF_E;
        float* MARG = ws + OFF_MARG;
        int* IDX = (int*)(ws + OFF_IDX);
        _Float16* CH = (_Float16*)(ws + OFF_CH);
        unsigned short* ZFH = (unsigned short*)(ws + OFF_ZFH);
        unsigned short* EFH = (unsigned short*)(ws + OFF_EFH);
        float* LOSSP = ws + OFF_LOSSP;

        k_pre<<<384, 256, 0, stream>>>(z, emb, ws);
        dim3 g(NROWS / 128, NE / 128);
        k_gemm<<<g, 256, 0, stream>>>(ZFH, EFH, S, E, CH);
        k_rescore<<<NROWS / 4, 256, 0, stream>>>(z, emb, S, E, MARG, ZFH, EFH, CH,
                                                 IDX, out + OUT_N + 1);
        k_out<<<NROWS / 32, 256, 0, stream>>>(z, emb, IDX, out, LOSSP);
        k_fin<<<1, 256, 0, stream>>>(LOSSP, out + OUT_N);
    } else {
        float* S = ws + FWS_S;
        float* E = ws + FWS_E;
        unsigned long long* KEYS = (unsigned long long*)(ws + FWS_KEY);
        int* IDX = (int*)(ws + FWS_IDX);
        float* LOSSP = ws + FWS_LOSSP;

        f_rowsum_z<<<NROWS / 256, 256, 0, stream>>>(z, S);
        f_rowsum_e<<<NE / 4, 256, 0, stream>>>(emb, E);
        hipMemsetAsync(KEYS, 0xFF, NROWS * sizeof(unsigned long long), stream);
        dim3 g(NROWS / 128, NE / 128);
        f_gemm_argmin<<<g, 256, 0, stream>>>(z, emb, S, E, KEYS);
        f_merge<<<NROWS / 256, 256, 0, stream>>>(KEYS, IDX, out + OUT_N + 1);
        k_out<<<NROWS / 32, 256, 0, stream>>>(z, emb, IDX, out, LOSSP);
        k_fin<<<1, 256, 0, stream>>>(LOSSP, out + OUT_N);
    }
}

// Round 10
// 328.840 us; speedup vs baseline: 1.0889x; 1.0889x over previous
//
#include <hip/hip_runtime.h>
#include <hip/hip_bf16.h>

#define NROWS 16384      // 16*32*32
#define EDIM  256
#define NE    8192
#define OUT_N 4194304    // 16*256*32*32

typedef _Float16 v8h __attribute__((ext_vector_type(8)));
typedef _Float16 v4h __attribute__((ext_vector_type(4)));
typedef float    v4f __attribute__((ext_vector_type(4)));

// ---- main-path ws layout (float units) ---- (16.2 MB < 17.1 MB proven)
#define OFF_S     0                        // 16384
#define OFF_E     16384                    // 8192
#define OFF_MARG  24576                    // 16384
#define OFF_IDX   40960                    // 16384 i32
#define OFF_CH    57600                    // 16384*128 fp16 = 1048576 float slots
#define OFF_ZFH   1106176                  // 16384*256 fp16 = 2097152 float slots
#define OFF_EFH   3203328                  // 8192*256 fp16 = 1048576 float slots
#define OFF_LOSSP 4251904                  // 512 block partials
#define WS_NEED_FLOATS 4252416

#define ESCALE   1048576.0f                // 2^20 (exact); descale 2^-19 on d
#define DESCALE  0x1p-19f

static __device__ __forceinline__ unsigned short to_fp16_bits(float v) {
    _Float16 h = (_Float16)v;
    return __builtin_bit_cast(unsigned short, h);
}

// =======================================================================
// k_pre (validated R6-R9, unchanged): z rows (S, MARG, z cvt fp16),
// emb (cvt*2^20 + E sums).
// =======================================================================
__global__ __launch_bounds__(256) void k_pre(const float* __restrict__ z,
                                             const float* __restrict__ emb,
                                             float* __restrict__ ws) {
    float* S = ws + OFF_S;
    float* E = ws + OFF_E;
    float* MARG = ws + OFF_MARG;
    unsigned short* zfh = (unsigned short*)(ws + OFF_ZFH);
    unsigned short* efh = (unsigned short*)(ws + OFF_EFH);

    const int blk = blockIdx.x, tid = threadIdx.x;

    __shared__ float T[64][260];
    __shared__ double SD[64][4];
    __shared__ double AD[64][4];

    if (blk < 256) {
        const int r0 = blk * 64;
        const int b = r0 >> 10, hw0 = r0 & 1023;   // 64-row tile never crosses b
        const int rr = tid & 63, kq = tid >> 6;
        const float* zp = z + (size_t)b * 262144 + hw0 + rr;
        double s = 0.0, a = 0.0;
#pragma unroll 8
        for (int kk = 0; kk < 64; ++kk) {
            int k = kq * 64 + kk;
            float v = zp[(size_t)k << 10];
            s += (double)v * (double)v;
            a += fabs((double)v);
            T[rr][k] = v;
        }
        SD[rr][kq] = s; AD[rr][kq] = a;
        __syncthreads();
        if (tid < 64) {
            double ss = SD[tid][0] + SD[tid][1] + SD[tid][2] + SD[tid][3];
            double aa = AD[tid][0] + AD[tid][1] + AD[tid][2] + AD[tid][3];
            S[r0 + tid] = (float)ss;
            MARG[r0 + tid] = 1.2e-4f + 6.5e-7f * (float)aa;
        }
        const int m = tid >> 2, koff = (tid & 3) * 64;
#pragma unroll
        for (int c = 0; c < 8; ++c) {
            unsigned short us[8];
#pragma unroll
            for (int j = 0; j < 8; ++j) us[j] = to_fp16_bits(T[m][koff + c * 8 + j]);
            *(uint4*)(zfh + (size_t)(r0 + m) * 256 + koff + c * 8) = *(uint4*)us;
        }
    } else {
        const int eb = blk - 256;
        const float* src = emb + (size_t)eb * 16384;
        unsigned short* dst = efh + (size_t)eb * 16384;
#pragma unroll
        for (int it = 0; it < 16; ++it) {
            int e4 = tid + it * 256;
            float4 v = ((const float4*)src)[e4];
            unsigned short us[4] = {to_fp16_bits(v.x * ESCALE), to_fp16_bits(v.y * ESCALE),
                                    to_fp16_bits(v.z * ESCALE), to_fp16_bits(v.w * ESCALE)};
            *(uint2*)(dst + (size_t)e4 * 4) = *(uint2*)us;
        }
        const int n0 = eb * 64;
        const int rr = tid & 63, kq = tid >> 6;
        const float* p = emb + (size_t)(n0 + rr) * 256 + kq * 64;
        double s = 0.0;
#pragma unroll 8
        for (int kk = 0; kk < 64; ++kk) { float v = p[kk]; s += (double)v * (double)v; }
        SD[rr][kq] = s;
        __syncthreads();
        if (tid < 64)
            E[n0 + tid] = (float)(SD[tid][0] + SD[tid][1] + SD[tid][2] + SD[tid][3]);
    }
}

// =======================================================================
// k_gemm (validated R6-R9, unchanged): fp16 MFMA 128x128, K=256; per-(row,
// 64-col chunk) min of d_approx stored fp16 rel to S[r]. Deterministic.
// =======================================================================
__global__ __launch_bounds__(256) void k_gemm(
    const unsigned short* __restrict__ zfh, const unsigned short* __restrict__ efh,
    const float* __restrict__ S, const float* __restrict__ E,
    _Float16* __restrict__ CH) {
    __shared__ __align__(16) unsigned short As[128 * 64];
    __shared__ __align__(16) unsigned short Bs[128 * 64];

    const int tid = threadIdx.x;
    const int lane = tid & 63, wave = tid >> 6;
    const int wm = (wave & 1) * 64, wn = (wave >> 1) * 64;
    const int row0 = blockIdx.x * 128, col0 = blockIdx.y * 128;
    const int lm = lane & 15, lq = lane >> 4;

    v4f acc[4][4];
#pragma unroll
    for (int i = 0; i < 4; ++i)
#pragma unroll
        for (int j = 0; j < 4; ++j) acc[i][j] = (v4f){0.f, 0.f, 0.f, 0.f};

    for (int kt = 0; kt < 4; ++kt) {
        const int kbase = kt * 64;
#pragma unroll
        for (int it = 0; it < 4; ++it) {
            int e = tid + it * 256;
            int m = e >> 3, c = e & 7;
            uint4 va = *(const uint4*)(zfh + (size_t)(row0 + m) * 256 + kbase + c * 8);
            *(uint4*)(As + m * 64 + ((c ^ (m & 7)) << 3)) = va;
            uint4 vb = *(const uint4*)(efh + (size_t)(col0 + m) * 256 + kbase + c * 8);
            *(uint4*)(Bs + m * 64 + ((c ^ (m & 7)) << 3)) = vb;
        }
        __syncthreads();
#pragma unroll
        for (int s = 0; s < 2; ++s) {
            v8h af[4], bfr[4];
#pragma unroll
            for (int fi = 0; fi < 4; ++fi) {
                int m = wm + fi * 16 + lm;
                int c = (s << 2) | lq;
                af[fi] = *(const v8h*)(As + m * 64 + ((c ^ (m & 7)) << 3));
            }
#pragma unroll
            for (int fj = 0; fj < 4; ++fj) {
                int n = wn + fj * 16 + lm;
                int c = (s << 2) | lq;
                bfr[fj] = *(const v8h*)(Bs + n * 64 + ((c ^ (n & 7)) << 3));
            }
#pragma unroll
            for (int fi = 0; fi < 4; ++fi)
#pragma unroll
                for (int fj = 0; fj < 4; ++fj)
                    acc[fi][fj] = __builtin_amdgcn_mfma_f32_16x16x32_f16(
                        af[fi], bfr[fj], acc[fi][fj], 0, 0, 0);
        }
        __syncthreads();
    }

    float Sl[16];
#pragma unroll
    for (int fi = 0; fi < 4; ++fi)
#pragma unroll
        for (int r = 0; r < 4; ++r)
            Sl[fi * 4 + r] = S[row0 + wm + fi * 16 + lq * 4 + r];
    float En[4];
#pragma unroll
    for (int fj = 0; fj < 4; ++fj) En[fj] = E[col0 + wn + fj * 16 + lm];

    float dmin[16];
#pragma unroll
    for (int fi = 0; fi < 4; ++fi)
#pragma unroll
        for (int r = 0; r < 4; ++r) {
            float dm = __builtin_inff();
#pragma unroll
            for (int fj = 0; fj < 4; ++fj) {
                float d = (Sl[fi * 4 + r] + En[fj]) - acc[fi][fj][r] * DESCALE;
                dm = fminf(dm, d);
            }
            dmin[fi * 4 + r] = dm;
        }
#pragma unroll
    for (int msk = 1; msk < 16; msk <<= 1)
#pragma unroll
        for (int i = 0; i < 16; ++i)
            dmin[i] = fminf(dmin[i], __shfl_xor(dmin[i], msk, 64));

    if (lm == 0) {
        const int cb = blockIdx.y * 2 + (wn >> 6);
#pragma unroll
        for (int i = 0; i < 16; ++i) {
            int fi = i >> 2, r = i & 3;
            int gm = row0 + wm + fi * 16 + lq * 4 + r;
            float rel = dmin[i] - Sl[i];             // Sterbenz: exact
            CH[(size_t)gm * 128 + cb] = (_Float16)rel;
        }
    }
}

// =======================================================================
// k_rescore v5: block = 32 consecutive rows, 1024 threads (16 waves,
// 2 rows/wave). fp32 z tile staged with FULL-LINE coalesced reads (z line
// = 32 hw x 4B = 128B, all consumed -> exactly 64 MB total). Refine:
// fp32-z (LDS broadcast) x fp16-emb (EFH, L2-resident; error strictly
// tighter than the validated R7/R8 bound, MB unchanged). Exact fp32 chain
// bit-identical (same values, same ascending-k fmaf order) reading z from
// LDS broadcast. Deterministic: no atomics, fixed ascending order.
// =======================================================================
__global__ __launch_bounds__(1024) void k_rescore(
    const float* __restrict__ z, const float* __restrict__ emb,
    const float* __restrict__ S, const float* __restrict__ E,
    const float* __restrict__ MARG,
    const unsigned short* __restrict__ efh,
    const _Float16* __restrict__ CH,
    int* __restrict__ IDX, float* __restrict__ idx_f) {
    __shared__ float zs[32][260];
    const int tid = threadIdx.x;
    const int r0 = blockIdx.x * 32;            // 32 consecutive rows, same b
    const int b = r0 >> 10, hw0 = r0 & 1023;
    const float* zb = z + ((size_t)b << 18) + hw0;

    // stage 32x256 fp32 z: float4 over hw (full 128B lines, coalesced)
#pragma unroll
    for (int it = 0; it < 2; ++it) {
        int slot = tid + it * 1024;            // 0..2047 float4 slots
        int c = slot >> 3, h4 = (slot & 7) << 2;
        float4 v = *(const float4*)(zb + (size_t)c * 1024 + h4);
        zs[h4 + 0][c] = v.x; zs[h4 + 1][c] = v.y;
        zs[h4 + 2][c] = v.z; zs[h4 + 3][c] = v.w;
    }
    __syncthreads();

    const int lane = tid & 63, wave = tid >> 6;   // 16 waves
#pragma unroll
    for (int rw = 0; rw < 2; ++rw) {
        const int rl = wave * 2 + rw;
        const int r = r0 + rl;

        float m0 = (float)CH[(size_t)r * 128 + lane];
        float m1 = (float)CH[(size_t)r * 128 + 64 + lane];
        float g = fminf(m0, m1);
#pragma unroll
        for (int off = 32; off; off >>= 1) g = fminf(g, __shfl_xor(g, off, 64));
        const float thr = g + MARG[r];
        const float MB  = 0.75f * MARG[r];
        const float Sr = S[r];

        unsigned long long p0 = __ballot(m0 <= thr);
        unsigned long long p1 = __ballot(m1 <= thr);

        unsigned long long key = ~0ull;
        float grun = __builtin_inff();
        for (int half = 0; half < 2; ++half) {
            unsigned long long pm = half ? p1 : p0;
            while (pm) {                       // wave-uniform, ascending chunks
                int c = __ffsll((long long)pm) - 1; pm &= pm - 1;
                const int cb = half * 64 + c;
                const int j = (cb << 6) | lane;
                // ---- refine: fp32 z (LDS broadcast) x fp16 emb (scaled 2^20)
                const v4h* ehp = (const v4h*)(efh + ((size_t)j << 8));
                float macc = 0.0f;
#pragma unroll 8
                for (int k4 = 0; k4 < 64; ++k4) {
                    v4h hv = ehp[k4];
                    macc = fmaf(zs[rl][k4 * 4 + 0], (float)hv.x, macc);
                    macc = fmaf(zs[rl][k4 * 4 + 1], (float)hv.y, macc);
                    macc = fmaf(zs[rl][k4 * 4 + 2], (float)hv.z, macc);
                    macc = fmaf(zs[rl][k4 * 4 + 3], (float)hv.w, macc);
                }
                float dref = (Sr + E[j]) - macc * DESCALE;
                float lmin = dref;
#pragma unroll
                for (int off = 32; off; off >>= 1)
                    lmin = fminf(lmin, __shfl_xor(lmin, off, 64));
                grun = fminf(grun, lmin);
                // superset-safe: stale-high grun only adds survivors
                unsigned long long sm = __ballot(dref <= grun + MB);
                while (sm) {                   // ~1.2 survivors/row, ascending
                    int s = __ffsll((long long)sm) - 1; sm &= sm - 1;
                    const int js = (cb << 6) | s;
                    // ---- exact fp32 chain (bit-identical): LDS-broadcast z,
                    // broadcast emb row, ascending k
                    const float4* ep4 = (const float4*)(emb + ((size_t)js << 8));
                    float m = 0.0f;
#pragma unroll 8
                    for (int k4 = 0; k4 < 64; ++k4) {
                        float4 e4 = ep4[k4];
                        m = fmaf(zs[rl][k4 * 4 + 0], e4.x, m);
                        m = fmaf(zs[rl][k4 * 4 + 1], e4.y, m);
                        m = fmaf(zs[rl][k4 * 4 + 2], e4.z, m);
                        m = fmaf(zs[rl][k4 * 4 + 3], e4.w, m);
                    }
                    float d = (Sr + E[js]) - 2.0f * m;   // d>0 -> bits monotone
                    unsigned long long kk =
                        ((unsigned long long)__float_as_uint(d) << 32) | (unsigned)js;
                    key = kk < key ? kk : key; // lane-uniform
                }
            }
        }
        if (lane == 0) {
            int j = (int)(key & 0xFFFFFFFFull);
            IDX[r] = j;
            idx_f[r] = (float)j;
        }
    }
}

// =======================================================================
// k_out v2 (validated R8/R9, unchanged) + k_fin (deterministic loss)
// =======================================================================
__global__ __launch_bounds__(256) void k_out(const float* __restrict__ z,
                                             const float* __restrict__ emb,
                                             const int* __restrict__ idx,
                                             float* __restrict__ out,
                                             float* __restrict__ lossp) {
    __shared__ __align__(16) float EB[32 * 260];
    __shared__ float red[256];
    __shared__ int ids[32];
    const int tid = threadIdx.x;
    const int r0 = blockIdx.x * 32;            // 32 consecutive rows, same b
    const int b = r0 >> 10, hw0 = r0 & 1023;

    if (tid < 32) ids[tid] = idx[r0 + tid];
    __syncthreads();
#pragma unroll
    for (int it = 0; it < 8; ++it) {
        int i = tid + it * 256;                // 0..2047
        int rr = i >> 6, k4 = i & 63;
        float4 v = *(const float4*)(emb + (size_t)ids[rr] * 256 + k4 * 4);
        *(float4*)(EB + rr * 260 + k4 * 4) = v;
    }
    __syncthreads();

    const float* zb = z + ((size_t)b << 18) + hw0;
    float*       ob = out + ((size_t)b << 18) + hw0;
    const int hq = tid & 7;
    const int cg = tid >> 3;
    float lsum = 0.0f;
#pragma unroll
    for (int it = 0; it < 8; ++it) {
        int c = it * 32 + cg;
        float4 zv = *(const float4*)(zb + (size_t)c * 1024 + hq * 4);
        float e0 = EB[(hq * 4 + 0) * 260 + c];
        float e1 = EB[(hq * 4 + 1) * 260 + c];
        float e2 = EB[(hq * 4 + 2) * 260 + c];
        float e3 = EB[(hq * 4 + 3) * 260 + c];
        float d0 = e0 - zv.x, d1 = e1 - zv.y, d2 = e2 - zv.z, d3 = e3 - zv.w;
        float4 ov = {zv.x + d0, zv.y + d1, zv.z + d2, zv.w + d3};
        *(float4*)(ob + (size_t)c * 1024 + hq * 4) = ov;
        lsum += d0 * d0 + d1 * d1 + d2 * d2 + d3 * d3;
    }
    red[tid] = lsum;
    __syncthreads();
    for (int off = 128; off; off >>= 1) {
        if (tid < off) red[tid] += red[tid + off];
        __syncthreads();
    }
    if (tid == 0) lossp[blockIdx.x] = red[0];
}

__global__ __launch_bounds__(256) void k_fin(const float* __restrict__ lossp,
                                             float* __restrict__ out_loss) {
    __shared__ float red[256];
    const int tid = threadIdx.x;
    red[tid] = lossp[tid] + lossp[tid + 256];
    __syncthreads();
    for (int off = 128; off; off >>= 1) {
        if (tid < off) red[tid] += red[tid + off];
        __syncthreads();
    }
    if (tid == 0) {
        float m = red[0] / 4194304.0f;
        out_loss[0] = m + 0.25f * m;
    }
}

// =======================================================================
// Fallback path (round-2 core, proven): used only if ws is too small.
// =======================================================================
#define FWS_S     0
#define FWS_E     (FWS_S + NROWS)
#define FWS_KEY   (FWS_E + NE)
#define FWS_IDX   (FWS_KEY + NROWS * 2)
#define FWS_LOSSP (FWS_IDX + NROWS)

__global__ void f_rowsum_z(const float* __restrict__ z, float* __restrict__ S) {
    int r = blockIdx.x * 256 + threadIdx.x;
    int b = r >> 10, hw = r & 1023;
    const float* p = z + (size_t)b * 262144 + hw;
    double s = 0.0;
#pragma unroll 8
    for (int c = 0; c < 256; ++c) { float v = p[(size_t)c * 1024]; s += (double)v * (double)v; }
    S[r] = (float)s;
}
__global__ void f_rowsum_e(const float* __restrict__ emb, float* __restrict__ E) {
    int row = blockIdx.x * 4 + (threadIdx.x >> 6);
    int lane = threadIdx.x & 63;
    const float* p = emb + (size_t)row * 256;
    double s = 0.0;
#pragma unroll
    for (int i = 0; i < 4; ++i) { float v = p[lane + i * 64]; s += (double)v * (double)v; }
    for (int off = 32; off; off >>= 1) s += __shfl_down(s, off, 64);
    if (lane == 0) E[row] = (float)s;
}
__global__ __launch_bounds__(256, 4) void f_gemm_argmin(
    const float* __restrict__ z, const float* __restrict__ emb,
    const float* __restrict__ S, const float* __restrict__ E,
    unsigned long long* __restrict__ keys) {
    __shared__ __align__(16) float As[32][128];
    __shared__ __align__(16) float Bs[32][133];
    const int tid = threadIdx.x;
    const int tx = tid & 15, ty = tid >> 4;
    const int row0 = blockIdx.x * 128, col0 = blockIdx.y * 128;
    const int b = row0 >> 10, hw0 = row0 & 1023;
    const float* zb = z + (size_t)b * 262144 + hw0;
    float acc[8][8];
#pragma unroll
    for (int i = 0; i < 8; ++i)
#pragma unroll
        for (int j = 0; j < 8; ++j) acc[i][j] = 0.0f;
    for (int kt = 0; kt < 8; ++kt) {
        const int kbase = kt * 32;
#pragma unroll
        for (int it = 0; it < 4; ++it) {
            int e = tid + it * 256;
            int k = e >> 5, m4 = (e & 31) << 2;
            *(float4*)&As[k][m4] = *(const float4*)(zb + (size_t)(kbase + k) * 1024 + m4);
        }
#pragma unroll
        for (int it = 0; it < 4; ++it) {
            int e = tid + it * 256;
            int n = e >> 3, k4 = (e & 7) << 2;
            float4 v = *(const float4*)(emb + (size_t)(col0 + n) * 256 + kbase + k4);
            Bs[k4 + 0][n] = v.x; Bs[k4 + 1][n] = v.y;
            Bs[k4 + 2][n] = v.z; Bs[k4 + 3][n] = v.w;
        }
        __syncthreads();
#pragma unroll 8
        for (int k = 0; k < 32; ++k) {
            float4 a0 = *(const float4*)&As[k][tx * 4];
            float4 a1 = *(const float4*)&As[k][64 + tx * 4];
            float4 b0 = *(const float4*)&Bs[k][ty * 4];
            float4 b1 = *(const float4*)&Bs[k][64 + ty * 4];
            float a_[8] = {a0.x, a0.y, a0.z, a0.w, a1.x, a1.y, a1.z, a1.w};
            float b_[8] = {b0.x, b0.y, b0.z, b0.w, b1.x, b1.y, b1.z, b1.w};
#pragma unroll
            for (int i = 0; i < 8; ++i)
#pragma unroll
                for (int j = 0; j < 8; ++j) acc[i][j] += a_[i] * b_[j];
        }
        __syncthreads();
    }
    float4 S0 = *(const float4*)(S + row0 + tx * 4);
    float4 S1 = *(const float4*)(S + row0 + 64 + tx * 4);
    float4 E0 = *(const float4*)(E + col0 + ty * 4);
    float4 E1 = *(const float4*)(E + col0 + 64 + ty * 4);
    float Sr[8] = {S0.x, S0.y, S0.z, S0.w, S1.x, S1.y, S1.z, S1.w};
    float Ec[8] = {E0.x, E0.y, E0.z, E0.w, E1.x, E1.y, E1.z, E1.w};
    unsigned long long best[8];
#pragma unroll
    for (int i = 0; i < 8; ++i) best[i] = ~0ull;
#pragma unroll
    for (int j = 0; j < 8; ++j) {
        int col = col0 + ((j < 4) ? (ty * 4 + j) : (64 + ty * 4 + j - 4));
#pragma unroll
        for (int i = 0; i < 8; ++i) {
            float t = Sr[i] + Ec[j];
            float d = t - 2.0f * acc[i][j];
            unsigned ud = __float_as_uint(d);
            ud = (ud & 0x80000000u) ? ~ud : (ud | 0x80000000u);
            unsigned long long key = ((unsigned long long)ud << 32) | (unsigned)col;
            if (key < best[i]) best[i] = key;
        }
    }
    __syncthreads();
    unsigned long long* Sk = (unsigned long long*)&As[0][0];
#pragma unroll
    for (int i = 0; i < 4; ++i) {
        Sk[ty * 128 + tx * 4 + i] = best[i];
        Sk[ty * 128 + 64 + tx * 4 + i] = best[4 + i];
    }
    __syncthreads();
    if (tid < 128) {
        unsigned long long m = ~0ull;
#pragma unroll
        for (int t = 0; t < 16; ++t) {
            unsigned long long v = Sk[t * 128 + tid];
            m = v < m ? v : m;
        }
        atomicMin(&keys[row0 + tid], m);
    }
}
__global__ void f_merge(const unsigned long long* __restrict__ keys,
                        int* __restrict__ idx, float* __restrict__ idx_f) {
    int r = blockIdx.x * 256 + threadIdx.x;
    int bestj = (int)(keys[r] & 0xFFFFFFFFull);
    idx[r] = bestj;
    idx_f[r] = (float)bestj;
}

extern "C" void kernel_launch(void* const* d_in, const int* in_sizes, int n_in,
                              void* d_out, int out_size, void* d_ws, size_t ws_size,
                              hipStream_t stream) {
    const float* z   = (const float*)d_in[0];
    const float* emb = (const float*)d_in[1];
    float* out = (float*)d_out;
    float* ws  = (float*)d_ws;

    if (ws_size >= (size_t)WS_NEED_FLOATS * 4) {
        float* S = ws + OFF_S;
        float* E = ws + OFF_E;
        float* MARG = ws + OFF_MARG;
        int* IDX = (int*)(ws + OFF_IDX);
        _Float16* CH = (_Float16*)(ws + OFF_CH);
        unsigned short* ZFH = (unsigned short*)(ws + OFF_ZFH);
        unsigned short* EFH = (unsigned short*)(ws + OFF_EFH);
        float* LOSSP = ws + OFF_LOSSP;

        k_pre<<<384, 256, 0, stream>>>(z, emb, ws);
        dim3 g(NROWS / 128, NE / 128);
        k_gemm<<<g, 256, 0, stream>>>(ZFH, EFH, S, E, CH);
        k_rescore<<<NROWS / 32, 1024, 0, stream>>>(z, emb, S, E, MARG, EFH, CH,
                                                   IDX, out + OUT_N + 1);
        k_out<<<NROWS / 32, 256, 0, stream>>>(z, emb, IDX, out, LOSSP);
        k_fin<<<1, 256, 0, stream>>>(LOSSP, out + OUT_N);
    } else {
        float* S = ws + FWS_S;
        float* E = ws + FWS_E;
        unsigned long long* KEYS = (unsigned long long*)(ws + FWS_KEY);
        int* IDX = (int*)(ws + FWS_IDX);
        float* LOSSP = ws + FWS_LOSSP;

        f_rowsum_z<<<NROWS / 256, 256, 0, stream>>>(z, S);
        f_rowsum_e<<<NE / 4, 256, 0, stream>>>(emb, E);
        hipMemsetAsync(KEYS, 0xFF, NROWS * sizeof(unsigned long long), stream);
        dim3 g(NROWS / 128, NE / 128);
        f_gemm_argmin<<<g, 256, 0, stream>>>(z, emb, S, E, KEYS);
        f_merge<<<NROWS / 256, 256, 0, stream>>>(KEYS, IDX, out + OUT_N + 1);
        k_out<<<NROWS / 32, 256, 0, stream>>>(z, emb, IDX, out, LOSSP);
        k_fin<<<1, 256, 0, stream>>>(LOSSP, out + OUT_N);
    }
}